// Round 1
// baseline (41.027 us; speedup 1.0000x reference)
//
#include <hip/hip_runtime.h>

// Segment-mean over SORTED batch_ids: one block per segment (graph).
// Each block binary-searches its contiguous row range [start, end) in ids,
// accumulates the row-sum with float4 coalesced loads, reduces in LDS,
// divides by count, writes the mean row.

__global__ __launch_bounds__(256) void segmean_kernel(
    const float* __restrict__ x,
    const int*   __restrict__ ids,
    float*       __restrict__ out,
    int N, int D)
{
    const int g = (int)blockIdx.x;

    // lower_bound(ids, g): first index with ids[idx] >= g
    int lo = 0, hi = N;
    while (lo < hi) {
        int mid = (lo + hi) >> 1;
        if (ids[mid] < g) lo = mid + 1; else hi = mid;
    }
    const int start = lo;
    // lower_bound(ids, g+1): first index with ids[idx] > g
    hi = N;
    while (lo < hi) {
        int mid = (lo + hi) >> 1;
        if (ids[mid] <= g) lo = mid + 1; else hi = mid;
    }
    const int end = lo;
    const int count = end - start;

    // D floats per row, float4 per thread -> tpr threads cover one row.
    const int tpr    = D >> 2;                 // threads per row (64 for D=256)
    const int rpi    = (int)blockDim.x / tpr;  // rows per iteration (4)
    const int t      = (int)threadIdx.x;
    const int rowoff = t / tpr;
    const int col    = (t % tpr) << 2;

    float4 acc = make_float4(0.f, 0.f, 0.f, 0.f);
    #pragma unroll 4
    for (int r = start + rowoff; r < end; r += rpi) {
        const float4 v = *reinterpret_cast<const float4*>(x + (size_t)r * (size_t)D + col);
        acc.x += v.x; acc.y += v.y; acc.z += v.z; acc.w += v.w;
    }

    __shared__ float4 sdata[256];
    sdata[t] = acc;
    __syncthreads();

    if (t < tpr) {
        float4 s = sdata[t];
        for (int k = 1; k < rpi; ++k) {
            const float4 v = sdata[t + k * tpr];
            s.x += v.x; s.y += v.y; s.z += v.z; s.w += v.w;
        }
        const float c = (float)count;   // empty segments ~impossible (p ~ e^-390); 0/0->NaN matches ref
        const float4 o = make_float4(s.x / c, s.y / c, s.z / c, s.w / c);
        *reinterpret_cast<float4*>(out + (size_t)g * (size_t)D + col) = o;
    }
}

extern "C" void kernel_launch(void* const* d_in, const int* in_sizes, int n_in,
                              void* d_out, int out_size, void* d_ws, size_t ws_size,
                              hipStream_t stream) {
    const float* x   = (const float*)d_in[0];
    const int*   ids = (const int*)d_in[1];
    float*       out = (float*)d_out;

    const int N = in_sizes[1];            // 200000 rows
    const int D = in_sizes[0] / N;        // 256 features
    const int G = out_size / D;           // 512 graphs

    dim3 grid(G), block(256);
    segmean_kernel<<<grid, block, 0, stream>>>(x, ids, out, N, D);
}